// Round 1
// baseline (242.043 us; speedup 1.0000x reference)
//
#include <hip/hip_runtime.h>

#define DEV_INLINE __device__ __forceinline__

// Numerically stable softplus: max(v,0) + log1p(exp(-|v|)), with fast
// hw transcendentals (v_exp_f32 / v_log_f32). Abs error ~1e-6, threshold 0.2.
DEV_INLINE float softplus_f(float v) {
    return fmaxf(v, 0.0f) + __logf(1.0f + __expf(-fabsf(v)));
}

// One thread processes 2 consecutive rows (tokens):
//   input:  2*6  floats = 3 aligned float4 loads
//   output: 2*36 floats = 18 aligned float4 stores
// Weights are read with wave-uniform addresses from __restrict__ const
// pointers -> compiler emits s_load into SGPRs (scalar cache), so the
// vector pipes see only FMAs; no LDS involved.
__global__ __launch_bounds__(256) void pb_kernel(
    const float* __restrict__ x,
    const float* __restrict__ W_in, const float* __restrict__ b_in,
    const float* __restrict__ W1,   const float* __restrict__ b1,
    const float* __restrict__ W2,   const float* __restrict__ b2,
    const float* __restrict__ W3,   const float* __restrict__ b3,
    const float* __restrict__ W4,   const float* __restrict__ b4,
    const float* __restrict__ W_out,const float* __restrict__ b_out,
    float* __restrict__ out, int n_pairs)
{
    const int tid = blockIdx.x * blockDim.x + threadIdx.x;
    if (tid >= n_pairs) return;

    // ---- load 2 rows of x (12 floats, 48B-aligned) ----
    const float4* xv = (const float4*)x + (size_t)tid * 3;
    float4 a0 = xv[0];
    float4 a1 = xv[1];
    float4 a2 = xv[2];
    float xin[2][6] = {
        { a0.x, a0.y, a0.z, a0.w, a1.x, a1.y },
        { a1.z, a1.w, a2.x, a2.y, a2.z, a2.w }
    };

    // ---- input layer 6 -> 8 ----
    float y[2][8];
    #pragma unroll
    for (int r = 0; r < 2; ++r) {
        #pragma unroll
        for (int o = 0; o < 8; ++o) {
            float acc = b_in[o];
            #pragma unroll
            for (int i = 0; i < 6; ++i)
                acc = fmaf(W_in[o * 6 + i], xin[r][i], acc);
            y[r][o] = softplus_f(acc);
        }
    }

    // ---- 4 hidden layers 8 -> 8 ----
    const float* Ws[4] = { W1, W2, W3, W4 };
    const float* bs[4] = { b1, b2, b3, b4 };
    #pragma unroll
    for (int l = 0; l < 4; ++l) {
        const float* __restrict__ W = Ws[l];
        const float* __restrict__ b = bs[l];
        float t[2][8];
        #pragma unroll
        for (int r = 0; r < 2; ++r) {
            #pragma unroll
            for (int o = 0; o < 8; ++o) {
                float acc = b[o];
                #pragma unroll
                for (int i = 0; i < 8; ++i)
                    acc = fmaf(W[o * 8 + i], y[r][i], acc);
                t[r][o] = softplus_f(acc);
            }
        }
        #pragma unroll
        for (int r = 0; r < 2; ++r)
            #pragma unroll
            for (int o = 0; o < 8; ++o)
                y[r][o] = t[r][o];
    }

    // ---- output layer 8 -> 15, assemble antisymmetric 6x6, store ----
    float4* ov = (float4*)out + (size_t)tid * 18;
    #pragma unroll
    for (int r = 0; r < 2; ++r) {
        float u[15];
        #pragma unroll
        for (int o = 0; o < 15; ++o) {
            float acc = b_out[o];
            #pragma unroll
            for (int i = 0; i < 8; ++i)
                acc = fmaf(W_out[o * 8 + i], y[r][i], acc);
            u[o] = acc;
        }

        // L[i][j] = u[k], L[j][i] = -u[k] over row-major triu (k=1), diag 0.
        float L[36];
        #pragma unroll
        for (int i = 0; i < 36; ++i) L[i] = 0.0f;
        int k = 0;
        #pragma unroll
        for (int i = 0; i < 6; ++i) {
            #pragma unroll
            for (int j = i + 1; j < 6; ++j) {
                L[i * 6 + j] = u[k];
                L[j * 6 + i] = -u[k];
                ++k;
            }
        }

        #pragma unroll
        for (int q = 0; q < 9; ++q)
            ov[r * 9 + q] = make_float4(L[4 * q + 0], L[4 * q + 1],
                                        L[4 * q + 2], L[4 * q + 3]);
    }
}

extern "C" void kernel_launch(void* const* d_in, const int* in_sizes, int n_in,
                              void* d_out, int out_size, void* d_ws, size_t ws_size,
                              hipStream_t stream) {
    const float* x     = (const float*)d_in[0];
    const float* W_in  = (const float*)d_in[1];
    const float* b_in  = (const float*)d_in[2];
    const float* W1    = (const float*)d_in[3];
    const float* b1    = (const float*)d_in[4];
    const float* W2    = (const float*)d_in[5];
    const float* b2    = (const float*)d_in[6];
    const float* W3    = (const float*)d_in[7];
    const float* b3    = (const float*)d_in[8];
    const float* W4    = (const float*)d_in[9];
    const float* b4    = (const float*)d_in[10];
    const float* W_out = (const float*)d_in[11];
    const float* b_out = (const float*)d_in[12];
    float* out = (float*)d_out;

    const int N = in_sizes[0] / 6;     // number of rows (B*T), even
    const int n_pairs = N / 2;         // 2 rows per thread
    const int block = 256;
    const int grid = (n_pairs + block - 1) / block;

    hipLaunchKernelGGL(pb_kernel, dim3(grid), dim3(block), 0, stream,
                       x, W_in, b_in, W1, b1, W2, b2, W3, b3, W4, b4,
                       W_out, b_out, out, n_pairs);
}

// Round 2
// 197.196 us; speedup vs baseline: 1.2274x; 1.2274x over previous
//
#include <hip/hip_runtime.h>

#define DEV_INLINE __device__ __forceinline__

// Numerically stable softplus: max(v,0) + log1p(exp(-|v|)).
DEV_INLINE float softplus_f(float v) {
    return fmaxf(v, 0.0f) + __logf(1.0f + __expf(-fabsf(v)));
}

// One thread = one row (token). Output staged through LDS so global stores
// are block-contiguous full cache lines (fixes the 1.72x HBM write
// amplification seen in R1: per-thread 288B regions -> partial-line RMW).
//
// LDS layout: sbuf[tid*9 + m] (float4 slots). Write phase: lane t, chunk m
// hits 4-bank group (t*9+m)%8 = (t+m)%8 -> uniform over the wave -> no net
// bank conflicts. Read phase: lane-consecutive slots -> conflict-free, and
// the corresponding global stores are 1 KiB contiguous per wave instruction.
__global__ __launch_bounds__(256) void pb_kernel(
    const float* __restrict__ x,
    const float* __restrict__ W_in, const float* __restrict__ b_in,
    const float* __restrict__ W1,   const float* __restrict__ b1,
    const float* __restrict__ W2,   const float* __restrict__ b2,
    const float* __restrict__ W3,   const float* __restrict__ b3,
    const float* __restrict__ W4,   const float* __restrict__ b4,
    const float* __restrict__ W_out,const float* __restrict__ b_out,
    float* __restrict__ out, int n_rows)
{
    __shared__ float4 sbuf[256 * 9];   // 36 KB: 256 rows x 36 floats

    const int tid = threadIdx.x;
    const int row_raw = blockIdx.x * 256 + tid;
    const int row = row_raw < n_rows ? row_raw : n_rows - 1;  // clamp (grid is exact anyway)

    // ---- load one row of x (6 floats, 24B stride -> three float2 loads) ----
    const float2* xv = (const float2*)(x + (size_t)row * 6);
    float2 p0 = xv[0], p1 = xv[1], p2 = xv[2];
    const float xin[6] = { p0.x, p0.y, p1.x, p1.y, p2.x, p2.y };

    // ---- input layer 6 -> 8 ----
    float y[8];
    #pragma unroll
    for (int o = 0; o < 8; ++o) {
        float acc = b_in[o];
        #pragma unroll
        for (int i = 0; i < 6; ++i)
            acc = fmaf(W_in[o * 6 + i], xin[i], acc);
        y[o] = softplus_f(acc);
    }

    // ---- 4 hidden layers 8 -> 8 ----
    const float* Ws[4] = { W1, W2, W3, W4 };
    const float* bs[4] = { b1, b2, b3, b4 };
    #pragma unroll
    for (int l = 0; l < 4; ++l) {
        const float* __restrict__ W = Ws[l];
        const float* __restrict__ b = bs[l];
        float t[8];
        #pragma unroll
        for (int o = 0; o < 8; ++o) {
            float acc = b[o];
            #pragma unroll
            for (int i = 0; i < 8; ++i)
                acc = fmaf(W[o * 8 + i], y[i], acc);
            t[o] = softplus_f(acc);
        }
        #pragma unroll
        for (int o = 0; o < 8; ++o) y[o] = t[o];
    }

    // ---- output layer 8 -> 15 ----
    float u[15];
    #pragma unroll
    for (int o = 0; o < 15; ++o) {
        float acc = b_out[o];
        #pragma unroll
        for (int i = 0; i < 8; ++i)
            acc = fmaf(W_out[o * 8 + i], y[i], acc);
        u[o] = acc;
    }

    // ---- assemble antisymmetric 6x6 into registers ----
    float L[36];
    #pragma unroll
    for (int i = 0; i < 36; ++i) L[i] = 0.0f;
    {
        int k = 0;
        #pragma unroll
        for (int i = 0; i < 6; ++i) {
            #pragma unroll
            for (int j = i + 1; j < 6; ++j) {
                L[i * 6 + j] = u[k];
                L[j * 6 + i] = -u[k];
                ++k;
            }
        }
    }

    // ---- stage to LDS (9 x ds_write_b128, bank-uniform) ----
    #pragma unroll
    for (int m = 0; m < 9; ++m)
        sbuf[tid * 9 + m] = make_float4(L[4 * m + 0], L[4 * m + 1],
                                        L[4 * m + 2], L[4 * m + 3]);

    __syncthreads();

    // ---- block-coalesced global store: 36 KB contiguous per block ----
    float4* dst = (float4*)out + (size_t)blockIdx.x * (256 * 9);
    const long long total_f4 = (long long)n_rows * 9;
    #pragma unroll
    for (int q = 0; q < 9; ++q) {
        const int idx = q * 256 + tid;
        const long long gidx = (long long)blockIdx.x * (256 * 9) + idx;
        if (gidx < total_f4)
            dst[idx] = sbuf[idx];
    }
}

extern "C" void kernel_launch(void* const* d_in, const int* in_sizes, int n_in,
                              void* d_out, int out_size, void* d_ws, size_t ws_size,
                              hipStream_t stream) {
    const float* x     = (const float*)d_in[0];
    const float* W_in  = (const float*)d_in[1];
    const float* b_in  = (const float*)d_in[2];
    const float* W1    = (const float*)d_in[3];
    const float* b1    = (const float*)d_in[4];
    const float* W2    = (const float*)d_in[5];
    const float* b2    = (const float*)d_in[6];
    const float* W3    = (const float*)d_in[7];
    const float* b3    = (const float*)d_in[8];
    const float* W4    = (const float*)d_in[9];
    const float* b4    = (const float*)d_in[10];
    const float* W_out = (const float*)d_in[11];
    const float* b_out = (const float*)d_in[12];
    float* out = (float*)d_out;

    const int n_rows = in_sizes[0] / 6;           // B*T = 1,048,576
    const int block = 256;
    const int grid = (n_rows + block - 1) / block;

    hipLaunchKernelGGL(pb_kernel, dim3(grid), dim3(block), 0, stream,
                       x, W_in, b_in, W1, b1, W2, b2, W3, b3, W4, b4,
                       W_out, b_out, out, n_rows);
}